// Round 1
// baseline (558.573 us; speedup 1.0000x reference)
//
#include <hip/hip_runtime.h>
#include <hip/hip_bf16.h>

// Problem constants (from reference): N=4096, D=512, H=256, O=256, M=8, K=2, F=512, C=2
#define N_TOK 4096
#define D_IN  512
#define H_DIM 256
#define O_DIM 256
#define M_EXP 8
#define F_DIM 512

// ---------------------------------------------------------------------------
// Gating: logits = x@Wg + bg, softmax over M=8, top-2, renormalized weights.
// One wave (64 lanes) per token. Writes coef[M][N] (combine weight, 0 if not
// selected), mask[M][N] (0/1), and accumulates gsum[2][8] (soft usage) and
// cnt[2][8] (hard counts) via block-level LDS reduction + global atomics.
// ---------------------------------------------------------------------------
__global__ __launch_bounds__(256) void gate_kernel(
    const float* __restrict__ Xb, const float* __restrict__ Xc,
    const float* __restrict__ Wg, const float* __restrict__ bg,
    float* __restrict__ coef_b, float* __restrict__ coef_c,
    float* __restrict__ mask_b, float* __restrict__ mask_c,
    float* __restrict__ gsum, float* __restrict__ cnt)
{
    const int mod = blockIdx.y;
    const float* X = mod ? Xc : Xb;
    float* coef = mod ? coef_c : coef_b;
    float* mask = mod ? mask_c : mask_b;
    const int wave = threadIdx.x >> 6;
    const int lane = threadIdx.x & 63;
    const int n = blockIdx.x * 4 + wave;

    __shared__ float s_g[M_EXP];
    __shared__ float s_c[M_EXP];
    if (threadIdx.x < M_EXP) { s_g[threadIdx.x] = 0.f; s_c[threadIdx.x] = 0.f; }
    __syncthreads();

    float acc[M_EXP] = {0.f,0.f,0.f,0.f,0.f,0.f,0.f,0.f};
    const float* xrow = X + (size_t)n * D_IN;
#pragma unroll
    for (int k = 0; k < 8; ++k) {
        const int d = lane + 64 * k;
        const float xv = xrow[d];
        const float* wr = Wg + d * M_EXP;
#pragma unroll
        for (int m = 0; m < M_EXP; ++m) acc[m] += xv * wr[m];
    }
#pragma unroll
    for (int off = 1; off < 64; off <<= 1) {
#pragma unroll
        for (int m = 0; m < M_EXP; ++m) acc[m] += __shfl_xor(acc[m], off, 64);
    }
    float g[M_EXP];
    float mx = -1e30f;
#pragma unroll
    for (int m = 0; m < M_EXP; ++m) { g[m] = acc[m] + bg[m]; mx = fmaxf(mx, g[m]); }
    float es = 0.f;
#pragma unroll
    for (int m = 0; m < M_EXP; ++m) { g[m] = expf(g[m] - mx); es += g[m]; }
    const float inv = 1.f / es;
#pragma unroll
    for (int m = 0; m < M_EXP; ++m) g[m] *= inv;

    // top-2 (first occurrence wins ties, matching lax.top_k)
    int i0 = 0; float v0 = g[0];
#pragma unroll
    for (int m = 1; m < M_EXP; ++m) if (g[m] > v0) { v0 = g[m]; i0 = m; }
    int i1 = -1; float v1 = -1e30f;
#pragma unroll
    for (int m = 0; m < M_EXP; ++m) if (m != i0 && g[m] > v1) { v1 = g[m]; i1 = m; }

    if (lane == 0) {
        const float wn = 1.f / (v0 + v1);
        coef[i0 * N_TOK + n] = v0 * wn;
        coef[i1 * N_TOK + n] = v1 * wn;
        mask[i0 * N_TOK + n] = 1.f;
        mask[i1 * N_TOK + n] = 1.f;
#pragma unroll
        for (int m = 0; m < M_EXP; ++m) atomicAdd(&s_g[m], g[m]);
        atomicAdd(&s_c[i0], 1.f);
        atomicAdd(&s_c[i1], 1.f);
    }
    __syncthreads();
    if (threadIdx.x < M_EXP) {
        atomicAdd(&gsum[mod * M_EXP + threadIdx.x], s_g[threadIdx.x]);
        atomicAdd(&cnt[mod * M_EXP + threadIdx.x], s_c[threadIdx.x]);
    }
}

// ---------------------------------------------------------------------------
// Expert MLPs, fused per 16-token tile. For each of 8 experts:
//   h = relu(x@W1[m]+b1[m]) [16,256], y = h@W2[m]+b2[m] [16,256]
// Epilogue folds: out[n,:] += coef[m][n]*y  (local, no atomics)
//                 sum_out[m,:] += modw * mask[m][n]*y  (LDS colsum + atomics)
// Grid: (N/16, 2 modalities). 256 threads; thread owns 4 rows x 4 cols.
// LDS ~49KB -> 2 blocks/CU.
// ---------------------------------------------------------------------------
#define TN 16
__global__ __launch_bounds__(256) void expert_kernel(
    const float* __restrict__ Xb, const float* __restrict__ Xc,
    const float* __restrict__ W1, const float* __restrict__ b1,
    const float* __restrict__ W2, const float* __restrict__ b2,
    const float* __restrict__ coef_b, const float* __restrict__ coef_c,
    const float* __restrict__ mask_b, const float* __restrict__ mask_c,
    float* __restrict__ out_b, float* __restrict__ out_c,
    float* __restrict__ sum_out)
{
    const int mod = blockIdx.y;
    const float* X    = mod ? Xc : Xb;
    const float* coef = mod ? coef_c : coef_b;
    const float* mask = mod ? mask_c : mask_b;
    float* outp = mod ? out_c : out_b;
    const float modw = mod ? 2.f : 1.f;

    __shared__ float xs[TN][D_IN];    // 32KB
    __shared__ float hs[TN][H_DIM];   // 16KB
    __shared__ float ssum[O_DIM];     // 1KB

    const int t = threadIdx.x;
    const int base = blockIdx.x * TN;

    {   // stage x tile (rows contiguous)
        const float* src = X + (size_t)base * D_IN;
#pragma unroll
        for (int k = 0; k < 8; ++k) {
            const int idx = k * 1024 + t * 4;
            *(float4*)&xs[0][idx] = *(const float4*)&src[idx];
        }
    }
    ssum[t] = 0.f;
    __syncthreads();

    const int r0 = (t >> 6) * 4;    // 4 rows per thread
    const int c0 = (t & 63) * 4;    // 4 cols per thread
    float oacc[4][4];
#pragma unroll
    for (int i = 0; i < 4; ++i)
#pragma unroll
        for (int j = 0; j < 4; ++j) oacc[i][j] = 0.f;

    for (int m = 0; m < M_EXP; ++m) {
        // ---------- h phase ----------
        float hacc[4][4];
        {
            const float4 bb = *(const float4*)&b1[m * H_DIM + c0];
#pragma unroll
            for (int i = 0; i < 4; ++i) {
                hacc[i][0] = bb.x; hacc[i][1] = bb.y; hacc[i][2] = bb.z; hacc[i][3] = bb.w;
            }
        }
        const float* w1p = W1 + (size_t)m * D_IN * H_DIM;
        for (int d = 0; d < D_IN; d += 4) {
            float w[4][4];
#pragma unroll
            for (int dd = 0; dd < 4; ++dd)
                *(float4*)w[dd] = *(const float4*)&w1p[(size_t)(d + dd) * H_DIM + c0];
#pragma unroll
            for (int i = 0; i < 4; ++i) {
                const float4 xv = *(const float4*)&xs[r0 + i][d];
                const float xa[4] = {xv.x, xv.y, xv.z, xv.w};
#pragma unroll
                for (int dd = 0; dd < 4; ++dd)
#pragma unroll
                    for (int j = 0; j < 4; ++j)
                        hacc[i][j] = fmaf(xa[dd], w[dd][j], hacc[i][j]);
            }
        }
#pragma unroll
        for (int i = 0; i < 4; ++i) {
            float4 hv;
            hv.x = fmaxf(hacc[i][0], 0.f); hv.y = fmaxf(hacc[i][1], 0.f);
            hv.z = fmaxf(hacc[i][2], 0.f); hv.w = fmaxf(hacc[i][3], 0.f);
            *(float4*)&hs[r0 + i][c0] = hv;
        }
        __syncthreads();

        // ---------- y phase ----------
        float yacc[4][4];
        {
            const float4 bb = *(const float4*)&b2[m * O_DIM + c0];
#pragma unroll
            for (int i = 0; i < 4; ++i) {
                yacc[i][0] = bb.x; yacc[i][1] = bb.y; yacc[i][2] = bb.z; yacc[i][3] = bb.w;
            }
        }
        const float* w2p = W2 + (size_t)m * H_DIM * O_DIM;
        for (int h = 0; h < H_DIM; h += 4) {
            float w[4][4];
#pragma unroll
            for (int dd = 0; dd < 4; ++dd)
                *(float4*)w[dd] = *(const float4*)&w2p[(size_t)(h + dd) * O_DIM + c0];
#pragma unroll
            for (int i = 0; i < 4; ++i) {
                const float4 hv = *(const float4*)&hs[r0 + i][h];
                const float ha[4] = {hv.x, hv.y, hv.z, hv.w};
#pragma unroll
                for (int dd = 0; dd < 4; ++dd)
#pragma unroll
                    for (int j = 0; j < 4; ++j)
                        yacc[i][j] = fmaf(ha[dd], w[dd][j], yacc[i][j]);
            }
        }

        // ---------- epilogue: combine + masked column sums ----------
        float part[4] = {0.f, 0.f, 0.f, 0.f};
#pragma unroll
        for (int i = 0; i < 4; ++i) {
            const int row = base + r0 + i;
            const float cf = coef[m * N_TOK + row];
            const float mk = mask[m * N_TOK + row];
#pragma unroll
            for (int j = 0; j < 4; ++j) {
                oacc[i][j] = fmaf(cf, yacc[i][j], oacc[i][j]);
                part[j] = fmaf(mk, yacc[i][j], part[j]);
            }
        }
#pragma unroll
        for (int j = 0; j < 4; ++j) atomicAdd(&ssum[c0 + j], part[j] * modw);
        __syncthreads();
        atomicAdd(&sum_out[m * O_DIM + t], ssum[t]);
        ssum[t] = 0.f;
        __syncthreads();   // orders ssum reset AND hs reuse for next expert
    }

#pragma unroll
    for (int i = 0; i < 4; ++i) {
        float4 ov;
        ov.x = oacc[i][0]; ov.y = oacc[i][1]; ov.z = oacc[i][2]; ov.w = oacc[i][3];
        *(float4*)&outp[(size_t)(base + r0 + i) * O_DIM + c0] = ov;
    }
}

// ---------------------------------------------------------------------------
// Fusion: combined = [out_b | out_c | out_c] [N,768]; fused = relu(@Wf + bf)
// Tile 16 rows; combined staged in LDS (48KB). Thread: 8 rows x 4 cols.
// ---------------------------------------------------------------------------
__global__ __launch_bounds__(256) void fuse_kernel(
    const float* __restrict__ out_b, const float* __restrict__ out_c,
    const float* __restrict__ Wf, const float* __restrict__ bf,
    float* __restrict__ fused)
{
    __shared__ float cs[16][768];   // 48KB
    const int t = threadIdx.x;
    const int base = blockIdx.x * 16;

#pragma unroll
    for (int k = 0; k < 4; ++k) {
        const int idx = k * 1024 + t * 4;
        const int r = idx >> 8, c = idx & 255;
        *(float4*)&cs[r][c] = *(const float4*)&out_b[(size_t)(base + r) * O_DIM + c];
    }
#pragma unroll
    for (int k = 0; k < 4; ++k) {
        const int idx = k * 1024 + t * 4;
        const int r = idx >> 8, c = idx & 255;
        const float4 v = *(const float4*)&out_c[(size_t)(base + r) * O_DIM + c];
        *(float4*)&cs[r][256 + c] = v;
        *(float4*)&cs[r][512 + c] = v;
    }
    __syncthreads();

    const int r0 = (t >> 7) * 8;
    const int c0 = (t & 127) * 4;
    float acc[8][4];
    {
        const float4 bb = *(const float4*)&bf[c0];
#pragma unroll
        for (int i = 0; i < 8; ++i) {
            acc[i][0] = bb.x; acc[i][1] = bb.y; acc[i][2] = bb.z; acc[i][3] = bb.w;
        }
    }
    for (int j = 0; j < 768; j += 2) {
        float w0[4], w1[4];
        *(float4*)w0 = *(const float4*)&Wf[(size_t)j * F_DIM + c0];
        *(float4*)w1 = *(const float4*)&Wf[(size_t)(j + 1) * F_DIM + c0];
#pragma unroll
        for (int i = 0; i < 8; ++i) {
            const float2 a = *(const float2*)&cs[r0 + i][j];
#pragma unroll
            for (int jj = 0; jj < 4; ++jj)
                acc[i][jj] += a.x * w0[jj] + a.y * w1[jj];
        }
    }
#pragma unroll
    for (int i = 0; i < 8; ++i) {
        float4 ov;
        ov.x = fmaxf(acc[i][0], 0.f); ov.y = fmaxf(acc[i][1], 0.f);
        ov.z = fmaxf(acc[i][2], 0.f); ov.w = fmaxf(acc[i][3], 0.f);
        *(float4*)&fused[(size_t)(base + r0 + i) * F_DIM + c0] = ov;
    }
}

// ---------------------------------------------------------------------------
// Classifier: output = fused @ Wc + bc  [N,2]. One wave per row.
// ---------------------------------------------------------------------------
__global__ __launch_bounds__(256) void cls_kernel(
    const float* __restrict__ fused, const float* __restrict__ Wc,
    const float* __restrict__ bc, float* __restrict__ out)
{
    const int lane = threadIdx.x & 63;
    const int n = blockIdx.x * 4 + (threadIdx.x >> 6);
    float a0 = 0.f, a1 = 0.f;
    const float* fr = fused + (size_t)n * F_DIM;
#pragma unroll
    for (int k = 0; k < 8; ++k) {
        const int f = lane + 64 * k;
        const float fv = fr[f];
        a0 = fmaf(fv, Wc[f * 2 + 0], a0);
        a1 = fmaf(fv, Wc[f * 2 + 1], a1);
    }
#pragma unroll
    for (int off = 1; off < 64; off <<= 1) {
        a0 += __shfl_xor(a0, off, 64);
        a1 += __shfl_xor(a1, off, 64);
    }
    if (lane == 0) {
        out[n * 2 + 0] = a0 + bc[0];
        out[n * 2 + 1] = a1 + bc[1];
    }
}

// ---------------------------------------------------------------------------
// Losses: eq_loss and distinctiveness loss. Single block.
// gsum/cnt layout: [2][8] (binary then cfg). sum_out: [8][256].
// ---------------------------------------------------------------------------
__global__ __launch_bounds__(256) void loss_kernel(
    const float* __restrict__ gsum, const float* __restrict__ cnt,
    const float* __restrict__ sum_out, float* __restrict__ dout)
{
    __shared__ float avg[M_EXP][O_DIM];
    __shared__ float rho_s[M_EXP];
    __shared__ float simv[28];
    __shared__ float prs[28];
    const int t = threadIdx.x;
    if (t < M_EXP) rho_s[t] = cnt[t] + 2.f * cnt[M_EXP + t];
    __syncthreads();
    for (int idx = t; idx < M_EXP * O_DIM; idx += 256) {
        const int m = idx >> 8;
        avg[m][idx & 255] = sum_out[idx] / fmaxf(rho_s[m], 1.f);
    }
    __syncthreads();
    if (t < 28) {
        int a = 0, p = t;
        while (p >= 7 - a) { p -= 7 - a; ++a; }
        const int b = a + 1 + p;
        float d2 = 0.f;
        for (int o = 0; o < O_DIM; ++o) {
            const float df = avg[a][o] - avg[b][o];
            d2 = fmaf(df, df, d2);
        }
        const bool pr = (rho_s[a] > 0.f) && (rho_s[b] > 0.f);
        simv[t] = pr ? expf(-0.5f * d2) : 0.f;
        prs[t]  = pr ? 1.f : 0.f;
    }
    __syncthreads();
    if (t == 0) {
        float s = 0.f, np = 0.f;
        for (int p = 0; p < 28; ++p) { s += simv[p]; np += prs[p]; }
        dout[N_TOK * 2 + 0] = -s / fmaxf(np, 1.f);
        float eq = 0.f;
        for (int m = 0; m < M_EXP; ++m) {
            const float rho = cnt[m] + 2.f * cnt[M_EXP + m];
            const float rh  = gsum[m] + 2.f * gsum[M_EXP + m];
            eq = fmaf(rho, rh, eq);
        }
        dout[N_TOK * 2 + 1] = eq / (float)M_EXP;
    }
}

// ---------------------------------------------------------------------------
extern "C" void kernel_launch(void* const* d_in, const int* in_sizes, int n_in,
                              void* d_out, int out_size, void* d_ws, size_t ws_size,
                              hipStream_t stream)
{
    const float* Xb = (const float*)d_in[0];
    const float* Xc = (const float*)d_in[1];
    // d_in[2] (vec_fcg) intentionally unused: reference source bug reuses cfg.
    const float* Wg = (const float*)d_in[3];
    const float* bg = (const float*)d_in[4];
    const float* W1 = (const float*)d_in[5];
    const float* b1 = (const float*)d_in[6];
    const float* W2 = (const float*)d_in[7];
    const float* b2 = (const float*)d_in[8];
    const float* Wf = (const float*)d_in[9];
    const float* bf = (const float*)d_in[10];
    const float* Wc = (const float*)d_in[11];
    const float* bc = (const float*)d_in[12];
    float* out = (float*)d_out;

    float* ws = (float*)d_ws;
    float* coef_b  = ws;                          // M*N = 32768
    float* coef_c  = coef_b + M_EXP * N_TOK;
    float* mask_b  = coef_c + M_EXP * N_TOK;
    float* mask_c  = mask_b + M_EXP * N_TOK;
    float* gsum    = mask_c + M_EXP * N_TOK;      // [2][8]
    float* cnt     = gsum + 16;                   // [2][8]
    float* sum_out = cnt + 16;                    // [8][256]
    float* out_b   = sum_out + M_EXP * O_DIM;     // [N][256]
    float* out_c   = out_b + (size_t)N_TOK * O_DIM;
    float* fused   = out_c + (size_t)N_TOK * O_DIM; // [N][512]

    // zero the write-sparse / atomic regions (coef, mask, gsum, cnt, sum_out)
    const size_t zero_bytes = (size_t)(4 * M_EXP * N_TOK + 32 + M_EXP * O_DIM) * sizeof(float);
    hipMemsetAsync(d_ws, 0, zero_bytes, stream);

    gate_kernel<<<dim3(N_TOK / 4, 2), 256, 0, stream>>>(
        Xb, Xc, Wg, bg, coef_b, coef_c, mask_b, mask_c, gsum, cnt);
    expert_kernel<<<dim3(N_TOK / TN, 2), 256, 0, stream>>>(
        Xb, Xc, W1, b1, W2, b2, coef_b, coef_c, mask_b, mask_c, out_b, out_c, sum_out);
    fuse_kernel<<<dim3(N_TOK / 16), 256, 0, stream>>>(out_b, out_c, Wf, bf, fused);
    cls_kernel<<<dim3(N_TOK / 4), 256, 0, stream>>>(fused, Wc, bc, out);
    loss_kernel<<<1, 256, 0, stream>>>(gsum, cnt, sum_out, out);
}

// Round 2
// 132.571 us; speedup vs baseline: 4.2134x; 4.2134x over previous
//
#include <hip/hip_runtime.h>
#include <hip/hip_bf16.h>

// Problem constants: N=4096, D=512, H=256, O=256, M=8, K=2, F=512, C=2
#define N_TOK 4096
#define D_IN  512
#define H_DIM 256
#define O_DIM 256
#define M_EXP 8
#define F_DIM 512

typedef __attribute__((ext_vector_type(8))) short bf16x8;   // 8 bf16 = 4 VGPRs (MFMA A/B frag)
typedef __attribute__((ext_vector_type(4))) float f32x4;    // MFMA C/D frag

// RNE f32 -> bf16 bits
__device__ __forceinline__ unsigned short f2bf(float f) {
    unsigned int u = __float_as_uint(f);
    u = (u + 0x7FFFu + ((u >> 16) & 1u)) >> 16;
    return (unsigned short)u;
}

// async global->LDS, 16B per lane; LDS dest = wave-uniform base + lane*16
__device__ __forceinline__ void gload_lds16(const void* g, void* l) {
    __builtin_amdgcn_global_load_lds(
        (const __attribute__((address_space(1))) unsigned int*)g,
        (__attribute__((address_space(3))) unsigned int*)l, 16, 0, 0);
}

// Swizzled LDS byte offsets. Tiles with 64B rows (4x16B slots): slot ^= (row>>1)&3.
__device__ __forceinline__ int sw64(int row, int lslot) {
    return row * 64 + ((lslot ^ ((row >> 1) & 3)) << 4);
}
// Hs tile: 512B rows (32x16B slots): slot ^= row&7 (low 3 bits).
__device__ __forceinline__ int swHs(int row, int lslot) {
    return row * 512 + ((lslot ^ (row & 7)) << 4);
}

// ---------------------------------------------------------------------------
// Gating (f32-exact): softmax over M=8 logits, top-2, renormalized weights.
// One wave per token. Also accumulates gsum (soft usage) and cnt (hard counts).
// ---------------------------------------------------------------------------
__global__ __launch_bounds__(256) void gate_kernel(
    const float* __restrict__ Xb, const float* __restrict__ Xc,
    const float* __restrict__ Wg, const float* __restrict__ bg,
    float* __restrict__ coef_b, float* __restrict__ coef_c,
    float* __restrict__ mask_b, float* __restrict__ mask_c,
    float* __restrict__ gsum, float* __restrict__ cnt)
{
    const int mod = blockIdx.y;
    const float* X = mod ? Xc : Xb;
    float* coef = mod ? coef_c : coef_b;
    float* mask = mod ? mask_c : mask_b;
    const int wave = threadIdx.x >> 6;
    const int lane = threadIdx.x & 63;
    const int n = blockIdx.x * 4 + wave;

    __shared__ float s_g[M_EXP];
    __shared__ float s_c[M_EXP];
    if (threadIdx.x < M_EXP) { s_g[threadIdx.x] = 0.f; s_c[threadIdx.x] = 0.f; }
    __syncthreads();

    float acc[M_EXP] = {0.f,0.f,0.f,0.f,0.f,0.f,0.f,0.f};
    const float* xrow = X + (size_t)n * D_IN;
#pragma unroll
    for (int k = 0; k < 8; ++k) {
        const int d = lane + 64 * k;
        const float xv = xrow[d];
        const float* wr = Wg + d * M_EXP;
#pragma unroll
        for (int m = 0; m < M_EXP; ++m) acc[m] += xv * wr[m];
    }
#pragma unroll
    for (int off = 1; off < 64; off <<= 1) {
#pragma unroll
        for (int m = 0; m < M_EXP; ++m) acc[m] += __shfl_xor(acc[m], off, 64);
    }
    float g[M_EXP];
    float mx = -1e30f;
#pragma unroll
    for (int m = 0; m < M_EXP; ++m) { g[m] = acc[m] + bg[m]; mx = fmaxf(mx, g[m]); }
    float es = 0.f;
#pragma unroll
    for (int m = 0; m < M_EXP; ++m) { g[m] = expf(g[m] - mx); es += g[m]; }
    const float inv = 1.f / es;
#pragma unroll
    for (int m = 0; m < M_EXP; ++m) g[m] *= inv;

    int i0 = 0; float v0 = g[0];
#pragma unroll
    for (int m = 1; m < M_EXP; ++m) if (g[m] > v0) { v0 = g[m]; i0 = m; }
    int i1 = -1; float v1 = -1e30f;
#pragma unroll
    for (int m = 0; m < M_EXP; ++m) if (m != i0 && g[m] > v1) { v1 = g[m]; i1 = m; }

    if (lane == 0) {
        const float wn = 1.f / (v0 + v1);
        coef[i0 * N_TOK + n] = v0 * wn;
        coef[i1 * N_TOK + n] = v1 * wn;
        mask[i0 * N_TOK + n] = 1.f;
        mask[i1 * N_TOK + n] = 1.f;
#pragma unroll
        for (int m = 0; m < M_EXP; ++m) atomicAdd(&s_g[m], g[m]);
        atomicAdd(&s_c[i0], 1.f);
        atomicAdd(&s_c[i1], 1.f);
    }
    __syncthreads();
    if (threadIdx.x < M_EXP) {
        atomicAdd(&gsum[mod * M_EXP + threadIdx.x], s_g[threadIdx.x]);
        atomicAdd(&cnt[mod * M_EXP + threadIdx.x], s_c[threadIdx.x]);
    }
}

// ---------------------------------------------------------------------------
// Prep: f32 [B][R][C] -> bf16 [B][C][R] (transpose + convert), 32x32 LDS tiles.
// ---------------------------------------------------------------------------
__global__ __launch_bounds__(256) void convT_kernel(
    const float* __restrict__ src, unsigned short* __restrict__ dst, int R, int C)
{
    __shared__ float tile[32][33];
    const int b = blockIdx.y;
    const int tpr = C >> 5;
    const int r0 = (blockIdx.x / tpr) * 32;
    const int c0 = (blockIdx.x % tpr) * 32;
    const float* s = src + (size_t)b * R * C;
    unsigned short* d = dst + (size_t)b * R * C;
    const int tr = threadIdx.x >> 3, q = threadIdx.x & 7;
    *(float4*)&tile[tr][q * 4] = *(const float4*)&s[(size_t)(r0 + tr) * C + c0 + q * 4];
    __syncthreads();
    ushort4 o;
    o.x = f2bf(tile[q * 4 + 0][tr]); o.y = f2bf(tile[q * 4 + 1][tr]);
    o.z = f2bf(tile[q * 4 + 2][tr]); o.w = f2bf(tile[q * 4 + 3][tr]);
    *(ushort4*)&d[(size_t)(c0 + tr) * R + r0 + q * 4] = o;
}

// WfT_eff[f][j] = Wf[j][f] + (j>=256 ? Wf[j+256][f] : 0), f,j in [0,512)
__global__ __launch_bounds__(256) void wf_fold_kernel(
    const float* __restrict__ Wf, unsigned short* __restrict__ dst)
{
    __shared__ float tile[32][33];
    const int j0 = (blockIdx.x >> 4) * 32;
    const int f0 = (blockIdx.x & 15) * 32;
    const int tr = threadIdx.x >> 3, q = threadIdx.x & 7;
    float4 v = *(const float4*)&Wf[(size_t)(j0 + tr) * F_DIM + f0 + q * 4];
    if (j0 >= 256) {
        const float4 v2 = *(const float4*)&Wf[(size_t)(j0 + tr + 256) * F_DIM + f0 + q * 4];
        v.x += v2.x; v.y += v2.y; v.z += v2.z; v.w += v2.w;
    }
    *(float4*)&tile[tr][q * 4] = v;
    __syncthreads();
    ushort4 o;
    o.x = f2bf(tile[q * 4 + 0][tr]); o.y = f2bf(tile[q * 4 + 1][tr]);
    o.z = f2bf(tile[q * 4 + 2][tr]); o.w = f2bf(tile[q * 4 + 3][tr]);
    *(ushort4*)&dst[(size_t)(f0 + tr) * 512 + j0 + q * 4] = o;
}

__global__ void init_out_kernel(const float* __restrict__ bc, float* __restrict__ out) {
    const int i = blockIdx.x * 256 + threadIdx.x;
    if (i < N_TOK * 2) out[i] = bc[i & 1];
}

// ---------------------------------------------------------------------------
// Expert MLP via MFMA. Grid (64 tiles, 16 mod-expert pairs). BM=64, BN=256,
// 4 waves x (64 rows x 64 cols), mfma_f32_16x16x32_bf16.
//   h = relu(X@W1+b1) -> LDS (bf16, swizzled); y = h@W2+b2 in regs.
// Epilogue: predicated atomic combine into out, masked col-sums -> sum_out.
// ---------------------------------------------------------------------------
__global__ __launch_bounds__(256, 3) void expert_mfma_kernel(
    const float* __restrict__ Xb, const float* __restrict__ Xc,
    const unsigned short* __restrict__ W1T, const unsigned short* __restrict__ W2T,
    const float* __restrict__ b1, const float* __restrict__ b2,
    const float* __restrict__ coef_b, const float* __restrict__ coef_c,
    const float* __restrict__ mask_b, const float* __restrict__ mask_c,
    float* __restrict__ out_b, float* __restrict__ out_c,
    float* __restrict__ sum_out)
{
    __shared__ __align__(16) char Xs[64 * 64];    // [64 rows][32 bf16], swizzled, 4KB
    __shared__ __align__(16) char Ws[256 * 64];   // [256 rows][32 bf16], swizzled, 16KB
    __shared__ __align__(16) char Hs[64 * 512];   // [64 rows][256 bf16], swizzled, 32KB
    __shared__ float coef_s[64];
    __shared__ float mask_s[64];

    const int t = threadIdx.x;
    const int w = t >> 6;
    const int l = t & 63;
    const int lr = l & 15;
    const int lk = l >> 4;
    const int pair = blockIdx.y;
    const int m = pair & 7;
    const int mod = pair >> 3;
    const float* X    = mod ? Xc : Xb;
    const float* coef = mod ? coef_c : coef_b;
    const float* mask = mod ? mask_c : mask_b;
    float* outp = mod ? out_c : out_b;
    const float modw = mod ? 2.f : 1.f;
    const int base = blockIdx.x * 64;
    const int wcol = w * 64;

    if (t < 64) {
        coef_s[t] = coef[m * N_TOK + base + t];
        mask_s[t] = mask[m * N_TOK + base + t];
    }

    // X staging: thread t owns phys 16B unit t -> (row=t>>2, pslot=t&3)
    const int xrow = t >> 2;
    const int xslot = (t & 3) ^ ((xrow >> 1) & 3);     // logical slot content
    const float* xsrc = X + (size_t)(base + xrow) * D_IN + xslot * 8;
    // W staging per (wave, sub): row = w*64 + s2*16 + l/4, pslot = l&3
    const int wrow_l = l >> 2;
    const int wpslot = l & 3;

    f32x4 acc[4][4];

    // ================= h phase: K=512, 16 steps of 32 =================
#pragma unroll
    for (int nj = 0; nj < 4; ++nj) {
        const float bv = b1[m * H_DIM + wcol + nj * 16 + lr];
#pragma unroll
        for (int mi = 0; mi < 4; ++mi) { f32x4 z = {bv, bv, bv, bv}; acc[mi][nj] = z; }
    }
    const unsigned short* w1base = W1T + (size_t)m * 256 * 512;
    for (int kc = 0; kc < 16; ++kc) {
        __syncthreads();
        {   // stage X chunk (f32 -> bf16)
            const float* s = xsrc + kc * 32;
            const float4 f0 = *(const float4*)s;
            const float4 f1 = *(const float4*)(s + 4);
            bf16x8 p;
            p[0] = (short)f2bf(f0.x); p[1] = (short)f2bf(f0.y);
            p[2] = (short)f2bf(f0.z); p[3] = (short)f2bf(f0.w);
            p[4] = (short)f2bf(f1.x); p[5] = (short)f2bf(f1.y);
            p[6] = (short)f2bf(f1.z); p[7] = (short)f2bf(f1.w);
            *(bf16x8*)&Xs[t * 16] = p;
        }
#pragma unroll
        for (int s2 = 0; s2 < 4; ++s2) {   // stage W1T chunk [256][32]
            const int row = w * 64 + s2 * 16 + wrow_l;
            const int lslot = wpslot ^ ((row >> 1) & 3);
            gload_lds16(w1base + (size_t)row * 512 + kc * 32 + lslot * 8,
                        &Ws[w * 4096 + s2 * 1024]);
        }
        __syncthreads();
        bf16x8 a[4], b[4];
#pragma unroll
        for (int mi = 0; mi < 4; ++mi)
            a[mi] = *(const bf16x8*)&Xs[sw64(mi * 16 + lr, lk)];
#pragma unroll
        for (int nj = 0; nj < 4; ++nj)
            b[nj] = *(const bf16x8*)&Ws[sw64(wcol + nj * 16 + lr, lk)];
#pragma unroll
        for (int mi = 0; mi < 4; ++mi)
#pragma unroll
            for (int nj = 0; nj < 4; ++nj)
                acc[mi][nj] = __builtin_amdgcn_mfma_f32_16x16x32_bf16(a[mi], b[nj], acc[mi][nj], 0, 0, 0);
    }

    // relu -> Hs (bf16, swizzled). D-frag: row=(lk*4+reg), col=lr within 16x16.
#pragma unroll
    for (int mi = 0; mi < 4; ++mi)
#pragma unroll
        for (int nj = 0; nj < 4; ++nj) {
            const int col = wcol + nj * 16 + lr;
            const int cslot = col >> 3;
            const int cbyte = (col & 7) * 2;
#pragma unroll
            for (int j = 0; j < 4; ++j) {
                const int row = mi * 16 + lk * 4 + j;
                *(unsigned short*)&Hs[row * 512 + ((cslot ^ (row & 7)) << 4) + cbyte] =
                    f2bf(fmaxf(acc[mi][nj][j], 0.f));
            }
        }

    // ================= y phase: K=256, 8 steps of 32 =================
#pragma unroll
    for (int nj = 0; nj < 4; ++nj) {
        const float bv = b2[m * O_DIM + wcol + nj * 16 + lr];
#pragma unroll
        for (int mi = 0; mi < 4; ++mi) { f32x4 z = {bv, bv, bv, bv}; acc[mi][nj] = z; }
    }
    const unsigned short* w2base = W2T + (size_t)m * 256 * 256;
    for (int kc = 0; kc < 8; ++kc) {
        __syncthreads();   // also makes Hs writes visible on first iteration
#pragma unroll
        for (int s2 = 0; s2 < 4; ++s2) {   // stage W2T chunk [256][32]
            const int row = w * 64 + s2 * 16 + wrow_l;
            const int lslot = wpslot ^ ((row >> 1) & 3);
            gload_lds16(w2base + (size_t)row * 256 + kc * 32 + lslot * 8,
                        &Ws[w * 4096 + s2 * 1024]);
        }
        __syncthreads();
        bf16x8 a[4], b[4];
#pragma unroll
        for (int mi = 0; mi < 4; ++mi) {
            const int row = mi * 16 + lr;
            a[mi] = *(const bf16x8*)&Hs[swHs(row, kc * 4 + lk)];
        }
#pragma unroll
        for (int nj = 0; nj < 4; ++nj)
            b[nj] = *(const bf16x8*)&Ws[sw64(wcol + nj * 16 + lr, lk)];
#pragma unroll
        for (int mi = 0; mi < 4; ++mi)
#pragma unroll
            for (int nj = 0; nj < 4; ++nj)
                acc[mi][nj] = __builtin_amdgcn_mfma_f32_16x16x32_bf16(a[mi], b[nj], acc[mi][nj], 0, 0, 0);
    }

    // ============ epilogue: top-k combine + masked column sums ============
    float sacc[4] = {0.f, 0.f, 0.f, 0.f};
#pragma unroll
    for (int mi = 0; mi < 4; ++mi)
#pragma unroll
        for (int j = 0; j < 4; ++j) {
            const int lrow = mi * 16 + lk * 4 + j;
            const float cf = coef_s[lrow];
            const float mk = mask_s[lrow];
            const size_t grow = (size_t)(base + lrow) * O_DIM;
#pragma unroll
            for (int nj = 0; nj < 4; ++nj) {
                const float v = acc[mi][nj][j];
                if (cf != 0.f) atomicAdd(&outp[grow + wcol + nj * 16 + lr], cf * v);
                sacc[nj] = fmaf(mk, v, sacc[nj]);
            }
        }
#pragma unroll
    for (int nj = 0; nj < 4; ++nj) {
        sacc[nj] += __shfl_xor(sacc[nj], 16, 64);
        sacc[nj] += __shfl_xor(sacc[nj], 32, 64);
    }
    if (lk == 0) {
#pragma unroll
        for (int nj = 0; nj < 4; ++nj)
            atomicAdd(&sum_out[m * O_DIM + wcol + nj * 16 + lr], sacc[nj] * modw);
    }
}

// ---------------------------------------------------------------------------
// Fusion + classifier, fused. combined=[out_b|out_c] (K=512 with folded WfT).
// fused = relu(combined@Wf_eff + bf); out += fused @ Wc (atomics, out pre-init
// with bc). Grid (128 row-tiles, 2 n-halves). BM=32, BN=256, 4 waves x 32x64.
// ---------------------------------------------------------------------------
__global__ __launch_bounds__(256, 4) void fuse_cls_kernel(
    const float* __restrict__ out_b, const float* __restrict__ out_c,
    const unsigned short* __restrict__ WfT, const float* __restrict__ bf,
    const float* __restrict__ Wc, float* __restrict__ out)
{
    __shared__ __align__(16) char As[32 * 64];    // [32 rows][32 bf16], 2KB
    __shared__ __align__(16) char Ws[256 * 64];   // 16KB
    const int t = threadIdx.x;
    const int w = t >> 6;
    const int l = t & 63;
    const int lr = l & 15, lk = l >> 4;
    const int base = blockIdx.x * 32;
    const int half = blockIdx.y;
    const int colbase = half * 256 + w * 64;

    f32x4 acc[2][4] = {};

    const int arow = t >> 2;
    const int aslot = (t & 3) ^ ((arow >> 1) & 3);
    const int wrow_l = l >> 2;
    const int wpslot = l & 3;

    for (int kc = 0; kc < 16; ++kc) {
        __syncthreads();
        if (t < 128) {
            const int gk = kc * 32 + aslot * 8;
            const float* src = (gk < 256 ? out_b : out_c) + (size_t)(base + arow) * 256 + (gk & 255);
            const float4 f0 = *(const float4*)src;
            const float4 f1 = *(const float4*)(src + 4);
            bf16x8 p;
            p[0] = (short)f2bf(f0.x); p[1] = (short)f2bf(f0.y);
            p[2] = (short)f2bf(f0.z); p[3] = (short)f2bf(f0.w);
            p[4] = (short)f2bf(f1.x); p[5] = (short)f2bf(f1.y);
            p[6] = (short)f2bf(f1.z); p[7] = (short)f2bf(f1.w);
            *(bf16x8*)&As[t * 16] = p;
        }
#pragma unroll
        for (int s2 = 0; s2 < 4; ++s2) {
            const int row = w * 64 + s2 * 16 + wrow_l;
            const int lslot = wpslot ^ ((row >> 1) & 3);
            gload_lds16(WfT + (size_t)(half * 256 + row) * 512 + kc * 32 + lslot * 8,
                        &Ws[w * 4096 + s2 * 1024]);
        }
        __syncthreads();
        bf16x8 a[2], b[4];
#pragma unroll
        for (int mi = 0; mi < 2; ++mi)
            a[mi] = *(const bf16x8*)&As[sw64(mi * 16 + lr, lk)];
#pragma unroll
        for (int nj = 0; nj < 4; ++nj)
            b[nj] = *(const bf16x8*)&Ws[sw64(w * 64 + nj * 16 + lr, lk)];
#pragma unroll
        for (int mi = 0; mi < 2; ++mi)
#pragma unroll
            for (int nj = 0; nj < 4; ++nj)
                acc[mi][nj] = __builtin_amdgcn_mfma_f32_16x16x32_bf16(a[mi], b[nj], acc[mi][nj], 0, 0, 0);
    }

    // epilogue: +bf, relu, x Wc, reduce over wave's 64 cols, atomic into out
#pragma unroll
    for (int mi = 0; mi < 2; ++mi)
#pragma unroll
        for (int j = 0; j < 4; ++j) {
            float p0 = 0.f, p1 = 0.f;
#pragma unroll
            for (int nj = 0; nj < 4; ++nj) {
                const int col = colbase + nj * 16 + lr;
                const float r = fmaxf(acc[mi][nj][j] + bf[col], 0.f);
                p0 = fmaf(r, Wc[col * 2 + 0], p0);
                p1 = fmaf(r, Wc[col * 2 + 1], p1);
            }
#pragma unroll
            for (int off = 1; off < 16; off <<= 1) {
                p0 += __shfl_xor(p0, off, 64);
                p1 += __shfl_xor(p1, off, 64);
            }
            if (lr == 0) {
                const int row = base + mi * 16 + lk * 4 + j;
                atomicAdd(&out[row * 2 + 0], p0);
                atomicAdd(&out[row * 2 + 1], p1);
            }
        }
}

// ---------------------------------------------------------------------------
// Losses (unchanged from round 1).
// ---------------------------------------------------------------------------
__global__ __launch_bounds__(256) void loss_kernel(
    const float* __restrict__ gsum, const float* __restrict__ cnt,
    const float* __restrict__ sum_out, float* __restrict__ dout)
{
    __shared__ float avg[M_EXP][O_DIM];
    __shared__ float rho_s[M_EXP];
    __shared__ float simv[28];
    __shared__ float prs[28];
    const int t = threadIdx.x;
    if (t < M_EXP) rho_s[t] = cnt[t] + 2.f * cnt[M_EXP + t];
    __syncthreads();
    for (int idx = t; idx < M_EXP * O_DIM; idx += 256) {
        const int m = idx >> 8;
        avg[m][idx & 255] = sum_out[idx] / fmaxf(rho_s[m], 1.f);
    }
    __syncthreads();
    if (t < 28) {
        int a = 0, p = t;
        while (p >= 7 - a) { p -= 7 - a; ++a; }
        const int b = a + 1 + p;
        float d2 = 0.f;
        for (int o = 0; o < O_DIM; ++o) {
            const float df = avg[a][o] - avg[b][o];
            d2 = fmaf(df, df, d2);
        }
        const bool pr = (rho_s[a] > 0.f) && (rho_s[b] > 0.f);
        simv[t] = pr ? expf(-0.5f * d2) : 0.f;
        prs[t]  = pr ? 1.f : 0.f;
    }
    __syncthreads();
    if (t == 0) {
        float s = 0.f, np = 0.f;
        for (int p = 0; p < 28; ++p) { s += simv[p]; np += prs[p]; }
        dout[N_TOK * 2 + 0] = -s / fmaxf(np, 1.f);
        float eq = 0.f;
        for (int m = 0; m < M_EXP; ++m) {
            const float rho = cnt[m] + 2.f * cnt[M_EXP + m];
            const float rh  = gsum[m] + 2.f * gsum[M_EXP + m];
            eq = fmaf(rho, rh, eq);
        }
        dout[N_TOK * 2 + 1] = eq / (float)M_EXP;
    }
}

// ---------------------------------------------------------------------------
extern "C" void kernel_launch(void* const* d_in, const int* in_sizes, int n_in,
                              void* d_out, int out_size, void* d_ws, size_t ws_size,
                              hipStream_t stream)
{
    const float* Xb = (const float*)d_in[0];
    const float* Xc = (const float*)d_in[1];
    // d_in[2] (vec_fcg) intentionally unused: reference source bug reuses cfg.
    const float* Wg = (const float*)d_in[3];
    const float* bg = (const float*)d_in[4];
    const float* W1 = (const float*)d_in[5];
    const float* b1 = (const float*)d_in[6];
    const float* W2 = (const float*)d_in[7];
    const float* b2 = (const float*)d_in[8];
    const float* Wf = (const float*)d_in[9];
    const float* bf = (const float*)d_in[10];
    const float* Wc = (const float*)d_in[11];
    const float* bc = (const float*)d_in[12];
    float* out = (float*)d_out;

    float* ws = (float*)d_ws;
    float* coef_b  = ws;                           // 32768
    float* coef_c  = coef_b + M_EXP * N_TOK;
    float* mask_b  = coef_c + M_EXP * N_TOK;
    float* mask_c  = mask_b + M_EXP * N_TOK;
    float* gsum    = mask_c + M_EXP * N_TOK;       // [2][8]
    float* cnt     = gsum + 16;                    // [2][8]
    float* sum_out = cnt + 16;                     // [8][256]
    float* out_b   = sum_out + M_EXP * O_DIM;      // [4096][256] f32 (atomic)
    float* out_c   = out_b + (size_t)N_TOK * O_DIM;
    unsigned short* W1T = (unsigned short*)(out_c + (size_t)N_TOK * O_DIM); // [8][256][512]
    unsigned short* W2T = W1T + (size_t)M_EXP * H_DIM * D_IN;              // [8][256][256]
    unsigned short* WfT = W2T + (size_t)M_EXP * O_DIM * H_DIM;             // [512][512]

    // zero all atomic-accumulated regions (coef..sum_out + out_b + out_c)
    const size_t zero_f = (size_t)(4 * M_EXP * N_TOK + 32 + M_EXP * O_DIM) + 2 * (size_t)N_TOK * O_DIM;
    hipMemsetAsync(d_ws, 0, zero_f * sizeof(float), stream);

    convT_kernel<<<dim3(16 * 8, M_EXP), 256, 0, stream>>>(W1, W1T, D_IN, H_DIM);
    convT_kernel<<<dim3(8 * 8, M_EXP), 256, 0, stream>>>(W2, W2T, H_DIM, O_DIM);
    wf_fold_kernel<<<dim3(256), 256, 0, stream>>>(Wf, WfT);
    init_out_kernel<<<dim3(32), 256, 0, stream>>>(bc, out);

    gate_kernel<<<dim3(N_TOK / 4, 2), 256, 0, stream>>>(
        Xb, Xc, Wg, bg, coef_b, coef_c, mask_b, mask_c, gsum, cnt);
    expert_mfma_kernel<<<dim3(N_TOK / 64, 16), 256, 0, stream>>>(
        Xb, Xc, W1T, W2T, b1, b2, coef_b, coef_c, mask_b, mask_c, out_b, out_c, sum_out);
    fuse_cls_kernel<<<dim3(N_TOK / 32, 2), 256, 0, stream>>>(out_b, out_c, WfT, bf, Wc, out);
    loss_kernel<<<1, 256, 0, stream>>>(gsum, cnt, sum_out, out);
}